// Round 4
// baseline (1589.403 us; speedup 1.0000x reference)
//
#include <hip/hip_runtime.h>
#include <hip/hip_bf16.h>

// PointSpatialConv: FPS + ball-query grouping + 2x (1x1 conv + BN + ReLU) + max over K.
// B=2, T=8, N=4096, M=1024, K=32, C1=64, C2=128.
//
// Round 4: fps UNCHANGED except grid 256->512 (2 blocks/CU) -- controlled A/B
// on the SCLK/governor theory. final_kernel: 4 m's per block (w2p reuse x4).

#define N_PTS   4096
#define M_PTS   1024
#define KNB     32

// packed f32 helpers (exact IEEE per-half, no contraction)
__device__ inline float2 pk_sub(float2 a, float2 b) {
  float2 d;
  asm("v_pk_add_f32 %0, %1, %2 neg_lo:[0,1] neg_hi:[0,1]" : "=v"(d) : "v"(a), "v"(b));
  return d;
}
__device__ inline float2 pk_mul(float2 a, float2 b) {
  float2 d;
  asm("v_pk_mul_f32 %0, %1, %2" : "=v"(d) : "v"(a), "v"(b));
  return d;
}
__device__ inline float2 pk_add(float2 a, float2 b) {
  float2 d;
  asm("v_pk_add_f32 %0, %1, %2" : "=v"(d) : "v"(a), "v"(b));
  return d;
}

#define DPPMAX(ctrl)                                                           \
  {                                                                            \
    unsigned _ohi = (unsigned)__builtin_amdgcn_update_dpp(                     \
        0, (int)(unsigned)(key >> 32), (ctrl), 0xF, 0xF, true);                \
    unsigned _olo = (unsigned)__builtin_amdgcn_update_dpp(                     \
        0, (int)(unsigned)(key & 0xFFFFFFFFull), (ctrl), 0xF, 0xF, true);      \
    unsigned long long _ok = ((unsigned long long)_ohi << 32) | _olo;          \
    if (_ok > key) key = _ok;                                                  \
  }

__global__ __launch_bounds__(256) void fps_kernel(const float* __restrict__ xyzs,
                                                  float* __restrict__ out) {
#pragma clang fp contract(off)
  const int bt  = blockIdx.x & 15;       // redundant copies per frame
  const int tid = threadIdx.x;
  __shared__ float sx[N_PTS], syy[N_PTS], szz[N_PTS];
  __shared__ ulonglong2 swk2[2][2];      // 4 wave-winner keys, dbuf
  __shared__ int sidx[M_PTS];

  const float* f = xyzs + (size_t)bt * (N_PTS * 3);
  for (int i = tid; i < N_PTS; i += 256) {
    sx[i]  = f[3 * i + 0];
    syy[i] = f[3 * i + 1];
    szz[i] = f[3 * i + 2];
  }
  if (tid == 0) sidx[0] = 0;
  __syncthreads();

  // pair layout: slot s=2j+h -> point index s*256+tid (index grows with slot)
  float2 px2[8], py2[8], pz2[8], dd2[8];
#pragma unroll
  for (int j = 0; j < 8; ++j) {
    int i0 = (2 * j) * 256 + tid, i1 = (2 * j + 1) * 256 + tid;
    px2[j] = {sx[i0], sx[i1]};
    py2[j] = {syy[i0], syy[i1]};
    pz2[j] = {szz[i0], szz[i1]};
    dd2[j] = {1e10f, 1e10f};
  }
  float wx = sx[0], wy = syy[0], wz = szz[0];

  for (int it = 1; it < M_PTS; ++it) {
    float2 wxx = {wx, wx}, wyy = {wy, wy}, wzz = {wz, wz};
    // packed distance update: d = (dx*dx + dy*dy) + dz*dz, then min
#pragma unroll
    for (int j = 0; j < 8; ++j) {
      float2 dx = pk_sub(px2[j], wxx);
      float2 dy = pk_sub(py2[j], wyy);
      float2 dz = pk_sub(pz2[j], wzz);
      float2 m1 = pk_mul(dx, dx);
      float2 m2 = pk_mul(dy, dy);
      float2 s  = pk_add(m1, m2);
      float2 m3 = pk_mul(dz, dz);
      float2 dt = pk_add(s, m3);
      dd2[j].x = fminf(dd2[j].x, dt.x);
      dd2[j].y = fminf(dd2[j].y, dt.y);
    }
    // adjacent-pair strict tree: challenger slot-set always above incumbent's,
    // so strict '>' alone preserves first-occurrence ties.
    float v8[8]; int s8[8];
#pragma unroll
    for (int a = 0; a < 8; ++a) {
      bool t = dd2[a].y > dd2[a].x;
      v8[a] = t ? dd2[a].y : dd2[a].x;
      s8[a] = 2 * a + (t ? 1 : 0);
    }
    float v4[4]; int s4[4];
#pragma unroll
    for (int a = 0; a < 4; ++a) {
      bool t = v8[2 * a + 1] > v8[2 * a];
      v4[a] = t ? v8[2 * a + 1] : v8[2 * a];
      s4[a] = t ? s8[2 * a + 1] : s8[2 * a];
    }
    float v2[2]; int s2v[2];
#pragma unroll
    for (int a = 0; a < 2; ++a) {
      bool t = v4[2 * a + 1] > v4[2 * a];
      v2[a] = t ? v4[2 * a + 1] : v4[2 * a];
      s2v[a] = t ? s4[2 * a + 1] : s4[2 * a];
    }
    bool t1 = v2[1] > v2[0];
    float bv = t1 ? v2[1] : v2[0];
    int   bs = t1 ? s2v[1] : s2v[0];
    int   gi = (bs << 8) + tid;
    unsigned long long key =
        ((unsigned long long)__float_as_uint(bv) << 32) | (unsigned)(~gi);

    // wave argmax via DPP; unique keys -> ties resolved inside u64 compare
    DPPMAX(0x111);  // row_shr:1
    DPPMAX(0x112);  // row_shr:2
    DPPMAX(0x114);  // row_shr:4
    DPPMAX(0x118);  // row_shr:8
    DPPMAX(0x142);  // row_bcast:15
    DPPMAX(0x143);  // row_bcast:31

    const int p = it & 1;
    if ((tid & 63) == 63)
      ((unsigned long long*)&swk2[p][0])[tid >> 6] = key;
    __syncthreads();
    ulonglong2 kA = swk2[p][0], kB = swk2[p][1];
    unsigned long long ka = kA.x > kA.y ? kA.x : kA.y;
    unsigned long long kb = kB.x > kB.y ? kB.x : kB.y;
    unsigned long long kw = ka > kb ? ka : kb;
    int bi = (int)(~(unsigned)(kw & 0xFFFFFFFFull));
    wx = sx[bi]; wy = syy[bi]; wz = szz[bi];
    if (tid == 0) sidx[it] = bi;
  }
  __syncthreads();
  float* orow = out + (size_t)bt * (M_PTS * 3);
  for (int i = tid; i < M_PTS; i += 256) {
    int ix = sidx[i];
    orow[3 * i + 0] = sx[ix];
    orow[3 * i + 1] = syy[ix];
    orow[3 * i + 2] = szz[ix];
  }
}

// ---------------------------------------------------------------- ball query
__global__ __launch_bounds__(256) void ball_kernel(const float* __restrict__ xyzs,
                                                   const float* __restrict__ refpts,
                                                   float* __restrict__ disp4) {
#pragma clang fp contract(off)
  const int lane = threadIdx.x & 63;
  const int gw   = (blockIdx.x << 2) + (threadIdx.x >> 6);   // ref point id, 0..16383
  const int bt   = gw >> 10;
  const float* f = xyzs + (size_t)bt * (N_PTS * 3);
  const float* r = refpts + (size_t)gw * 3;
  const float rx = r[0], ry = r[1], rz = r[2];
  float* dout = disp4 + (size_t)gw * (KNB * 4);

  int filled = 0;
  float p0x = 0.f, p0y = 0.f, p0z = 0.f;
  bool got0 = false;

  for (int base = 0; base < N_PTS; base += 64) {
    if (filled >= KNB) break;
    int j = base + lane;
    float x = f[3 * j], y = f[3 * j + 1], z = f[3 * j + 2];
    float dx = rx - x, dy = ry - y, dz = rz - z;
    float d2 = (dx * dx + dy * dy) + dz * dz;     // exact numpy order
    bool pred = d2 < 0.81f;                       // == f32(0.9*0.9 in f64)
    unsigned long long mk = __ballot(pred);
    if (!got0 && mk) {                            // wave-uniform
      int src = __builtin_ctzll(mk);
      p0x = __shfl(-dx, src); p0y = __shfl(-dy, src); p0z = __shfl(-dz, src);
      got0 = true;
    }
    int slot = filled + __popcll(mk & ((1ull << lane) - 1));
    if (pred && slot < KNB) {
      float4 v; v.x = -dx; v.y = -dy; v.z = -dz; v.w = 0.f;  // xyz - ref
      *(float4*)(dout + slot * 4) = v;
    }
    filled += __popcll(mk);
  }
  if (filled < KNB) {                             // pad with first neighbor
    for (int s = filled + lane; s < KNB; s += 64) {
      float4 v; v.x = p0x; v.y = p0y; v.z = p0z; v.w = 0.f;
      *(float4*)(dout + s * 4) = v;
    }
  }
}

// ---------------------------------------------------------------- BN1 moments
__global__ __launch_bounds__(256) void stats1_kernel(const float* __restrict__ disp4,
                                                     float* __restrict__ acc) {
  const int t = blockIdx.x >> 5, chunk = blockIdx.x & 31;
  const int tid = threadIdx.x;
  float s[9];
#pragma unroll
  for (int q = 0; q < 9; ++q) s[q] = 0.f;
  for (int i = tid; i < 2048; i += 256) {
    int smp = (chunk << 11) + i;                                    // sample in [0,65536)
    size_t flat = ((size_t)(smp >> 15) << 18) + ((size_t)t << 15) + (smp & 32767);
    float4 v = ((const float4*)disp4)[flat];
    s[0] += v.x;       s[1] += v.y;       s[2] += v.z;
    s[3] += v.x * v.x; s[4] += v.y * v.y; s[5] += v.z * v.z;
    s[6] += v.x * v.y; s[7] += v.x * v.z; s[8] += v.y * v.z;
  }
#pragma unroll
  for (int q = 0; q < 9; ++q) {
#pragma unroll
    for (int off = 1; off < 64; off <<= 1) s[q] += __shfl_xor(s[q], off);
  }
  if ((tid & 63) == 0) {
    float* a = acc + t * 9;
#pragma unroll
    for (int q = 0; q < 9; ++q) atomicAdd(&a[q], s[q]);
  }
}

__global__ void fold1_kernel(const float* __restrict__ acc, const float* __restrict__ W1,
                             const float* __restrict__ g1, const float* __restrict__ b1,
                             float* __restrict__ w1p) {
  const int t = blockIdx.x, c = threadIdx.x;
  const float inv_n = 1.0f / 65536.0f;
  const float* a = acc + t * 9;
  float mx = a[0] * inv_n, my = a[1] * inv_n, mz = a[2] * inv_n;
  float Sxx = a[3] * inv_n, Syy = a[4] * inv_n, Szz = a[5] * inv_n;
  float Sxy = a[6] * inv_n, Sxz = a[7] * inv_n, Syz = a[8] * inv_n;
  float w0 = W1[c * 4], w1 = W1[c * 4 + 1], w2 = W1[c * 4 + 2];
  float mean = w0 * mx + w1 * my + w2 * mz;
  float E2 = w0 * w0 * Sxx + w1 * w1 * Syy + w2 * w2 * Szz
           + 2.f * (w0 * w1 * Sxy + w0 * w2 * Sxz + w1 * w2 * Syz);
  float var = E2 - mean * mean;
  float al = g1[c] / sqrtf(var + 1e-5f);
  float4 o; o.x = w0 * al; o.y = w1 * al; o.z = w2 * al; o.w = b1[c] - mean * al;
  ((float4*)w1p)[t * 64 + c] = o;
}

// ---------------------------------------------------------------- Gram of y1
__global__ __launch_bounds__(256) void gram_kernel(const float* __restrict__ disp4,
                                                   const float* __restrict__ w1p,
                                                   float* __restrict__ sumy,
                                                   float* __restrict__ G) {
  const int t = blockIdx.x >> 5, chunk = blockIdx.x & 31;
  const int tid = threadIdx.x;
  __shared__ float4 sdisp[32];
  __shared__ float  yt[32][64];
  __shared__ float  red[256];

  const int c = tid & 63, s0 = tid >> 6;
  float4 wc = ((const float4*)w1p)[t * 64 + c];
  const int r0 = (tid >> 4) << 2, q0 = (tid & 15) << 2;
  float acc[16];
#pragma unroll
  for (int q = 0; q < 16; ++q) acc[q] = 0.f;
  float ysum = 0.f;

  for (int b = 0; b < 64; ++b) {
    int sb = (chunk << 11) + (b << 5);
    if (tid < 32) {
      int smp = sb + tid;
      size_t flat = ((size_t)(smp >> 15) << 18) + ((size_t)t << 15) + (smp & 32767);
      sdisp[tid] = ((const float4*)disp4)[flat];
    }
    __syncthreads();
#pragma unroll
    for (int u = 0; u < 8; ++u) {
      int s = s0 * 8 + u;
      float4 d = sdisp[s];
      float y = wc.x * d.x + wc.y * d.y + wc.z * d.z + wc.w;
      y = y > 0.f ? y : 0.f;
      yt[s][c] = y;
      ysum += y;
    }
    __syncthreads();
#pragma unroll
    for (int s = 0; s < 32; ++s) {
      float4 av = *(const float4*)&yt[s][r0];
      float4 bv = *(const float4*)&yt[s][q0];
      acc[0]  += av.x * bv.x; acc[1]  += av.x * bv.y; acc[2]  += av.x * bv.z; acc[3]  += av.x * bv.w;
      acc[4]  += av.y * bv.x; acc[5]  += av.y * bv.y; acc[6]  += av.y * bv.z; acc[7]  += av.y * bv.w;
      acc[8]  += av.z * bv.x; acc[9]  += av.z * bv.y; acc[10] += av.z * bv.z; acc[11] += av.z * bv.w;
      acc[12] += av.w * bv.x; acc[13] += av.w * bv.y; acc[14] += av.w * bv.z; acc[15] += av.w * bv.w;
    }
    __syncthreads();
  }
  red[tid] = ysum;
  __syncthreads();
  if (tid < 64) {
    float v = red[tid] + red[tid + 64] + red[tid + 128] + red[tid + 192];
    atomicAdd(&sumy[t * 64 + tid], v);
  }
  float* Gp = G + t * 4096;
#pragma unroll
  for (int i = 0; i < 4; ++i)
#pragma unroll
    for (int j2 = 0; j2 < 4; ++j2)
      atomicAdd(&Gp[(r0 + i) * 64 + q0 + j2], acc[i * 4 + j2]);
}

// ---------------------------------------------------------------- BN2 fold
__global__ __launch_bounds__(256) void fold2a_kernel(const float* __restrict__ G,
                                                     const float* __restrict__ W2,
                                                     float* __restrict__ P) {
  const int t = blockIdx.x >> 5, grp = blockIdx.x & 31;
  const int idx = (grp << 8) + threadIdx.x;   // 0..8191
  const int i = idx >> 7, c2 = idx & 127;
  const float* g = G + t * 4096 + i * 64;
  const float* w = W2 + c2 * 64;
  float accv = 0.f;
#pragma unroll
  for (int j = 0; j < 64; ++j) accv += g[j] * w[j];
  P[t * 8192 + i * 128 + c2] = accv;
}

__global__ __launch_bounds__(256) void fold2b_kernel(const float* __restrict__ P,
    const float* __restrict__ sumy, const float* __restrict__ W2,
    const float* __restrict__ g2, const float* __restrict__ b2,
    float* __restrict__ w2p, float* __restrict__ beta2) {
  const int gidx = blockIdx.x * 256 + threadIdx.x;  // 0..1023
  const int t = gidx >> 7, c2 = gidx & 127;
  const float inv_n = 1.f / 65536.f;
  const float* w = W2 + c2 * 64;
  float mean2 = 0.f, E2 = 0.f;
#pragma unroll
  for (int j = 0; j < 64; ++j) mean2 += w[j] * (sumy[t * 64 + j] * inv_n);
  const float* p = P + t * 8192 + c2;
#pragma unroll
  for (int i2 = 0; i2 < 64; ++i2) E2 += w[i2] * p[i2 * 128];
  E2 *= inv_n;
  float var = E2 - mean2 * mean2;
  float al = g2[c2] / sqrtf(var + 1e-5f);
  float be = b2[c2] - mean2 * al;
  beta2[t * 128 + c2] = be;
  float* wo = w2p + (size_t)(t * 128 + c2) * 64;
#pragma unroll
  for (int j = 0; j < 64; ++j) wo[j] = al * w[j];
}

// ---------------------------------------------------------------- final fused GEMM + max_k
// 4 m's per block: w2r register load amortized 4x, 4x fewer blocks.
__global__ __launch_bounds__(256) void final_kernel(
    const float* __restrict__ disp4, const float* __restrict__ w1p,
    const float* __restrict__ w2p, const float* __restrict__ beta2,
    float* __restrict__ outfeat) {
  const int bid = blockIdx.x;        // 4096 = one (bt, m-quad)
  const int bt = bid >> 8, mbase = (bid & 255) << 2;
  const int t = bt & 7;
  const int tid = threadIdx.x;
  __shared__ float4 sdisp[128];      // 4 m x 32 nb
  __shared__ float  sy[128][64];     // 32 KB
  __shared__ float  red[4][128];

  if (tid < 128)
    sdisp[tid] = ((const float4*)disp4)[(size_t)(bt * 1024 + mbase) * 32 + tid];
  const int c = tid & 63;
  float4 w1c = ((const float4*)w1p)[t * 64 + c];
  __syncthreads();

  const int s0 = tid >> 6;           // 0..3
#pragma unroll
  for (int u = 0; u < 32; ++u) {     // each thread: 32 y's (4m x 8s per c)
    int s = s0 * 32 + u;             // 0..127
    float4 d = sdisp[s];
    float y = w1c.x * d.x + w1c.y * d.y + w1c.z * d.z + w1c.w;
    sy[s][c] = y > 0.f ? y : 0.f;
  }

  const int c2 = tid & 127, kh = tid >> 7;
  const float* wr = w2p + (size_t)(t * 128 + c2) * 64;
  float w2r[64];
#pragma unroll
  for (int q = 0; q < 16; ++q) {
    float4 v = ((const float4*)wr)[q];
    w2r[4 * q] = v.x; w2r[4 * q + 1] = v.y; w2r[4 * q + 2] = v.z; w2r[4 * q + 3] = v.w;
  }
  const float b2v = beta2[t * 128 + c2];
  __syncthreads();

#pragma unroll
  for (int mi = 0; mi < 4; ++mi) {
    float mx = 0.0f;                                // relu output >= 0
#pragma unroll
    for (int ki = 0; ki < 16; ++ki) {
      int k = mi * 32 + kh * 16 + ki;
      float a0 = b2v;
#pragma unroll
      for (int j = 0; j < 64; j += 4) {
        float4 yv = *(const float4*)&sy[k][j];
        a0 += yv.x * w2r[j] + yv.y * w2r[j + 1] + yv.z * w2r[j + 2] + yv.w * w2r[j + 3];
      }
      mx = fmaxf(mx, a0);
    }
    if (kh == 1) red[mi][c2] = mx;
    __syncthreads();
    if (kh == 0) {
      mx = fmaxf(mx, red[mi][c2]);
      outfeat[((size_t)(bt * 128 + c2)) * 1024 + mbase + mi] = mx;
    }
  }
}

// ---------------------------------------------------------------- launch
extern "C" void kernel_launch(void* const* d_in, const int* in_sizes, int n_in,
                              void* d_out, int out_size, void* d_ws, size_t ws_size,
                              hipStream_t stream) {
  const float* xyzs = (const float*)d_in[0];
  const float* W1   = (const float*)d_in[1];
  const float* g1   = (const float*)d_in[2];
  const float* b1   = (const float*)d_in[3];
  const float* W2   = (const float*)d_in[4];
  const float* g2   = (const float*)d_in[5];
  const float* b2   = (const float*)d_in[6];
  float* out = (float*)d_out;
  float* ws  = (float*)d_ws;

  float* disp4 = ws;                 // 2,097,152 floats (B,T,M,K,4)
  float* acc   = ws + 2097152;       // 72
  float* sumy  = ws + 2097224;       // 512
  float* G     = ws + 2097736;       // 32768
  float* w1p   = ws + 2130504;       // 2048
  float* P     = ws + 2132552;       // 65536
  float* w2p   = ws + 2198088;       // 65536
  float* beta2 = ws + 2263624;       // 1024   (total ~8.6 MB)

  hipMemsetAsync(acc, 0, (72 + 512 + 32768) * sizeof(float), stream);
  fps_kernel   <<<512,   256, 0, stream>>>(xyzs, out);   // 32 copies/frame, 2 blocks/CU
  ball_kernel  <<<4096,  256, 0, stream>>>(xyzs, out, disp4);
  stats1_kernel<<<256,   256, 0, stream>>>(disp4, acc);
  fold1_kernel <<<8,     64,  0, stream>>>(acc, W1, g1, b1, w1p);
  gram_kernel  <<<256,   256, 0, stream>>>(disp4, w1p, sumy, G);
  fold2a_kernel<<<256,   256, 0, stream>>>(G, W2, P);
  fold2b_kernel<<<4,     256, 0, stream>>>(P, sumy, W2, g2, b2, w2p, beta2);
  final_kernel <<<4096,  256, 0, stream>>>(disp4, w1p, w2p, beta2, out + 49152);
}

// Round 5
// 1173.497 us; speedup vs baseline: 1.3544x; 1.3544x over previous
//
#include <hip/hip_runtime.h>
#include <hip/hip_bf16.h>

// PointSpatialConv: FPS + ball-query grouping + 2x (1x1 conv + BN + ReLU) + max over K.
// B=2, T=8, N=4096, M=1024, K=32, C1=64, C2=128.
//
// Round 5: fps rewritten: 512 thr/block (2 waves/SIMD interleave one chain),
// consecutive point layout -> f32-only DPP max + ballot/ctz index recovery,
// (val,gi) cross-wave select. Grid 256 (1 block/CU, clock ~0.8GHz plateau).
// final_kernel keeps round-4 4-m form. Everything else unchanged.

#define N_PTS   4096
#define M_PTS   1024
#define KNB     32

// packed f32 helpers (exact IEEE per-half, no contraction)
__device__ inline float2 pk_sub(float2 a, float2 b) {
  float2 d;
  asm("v_pk_add_f32 %0, %1, %2 neg_lo:[0,1] neg_hi:[0,1]" : "=v"(d) : "v"(a), "v"(b));
  return d;
}
__device__ inline float2 pk_mul(float2 a, float2 b) {
  float2 d;
  asm("v_pk_mul_f32 %0, %1, %2" : "=v"(d) : "v"(a), "v"(b));
  return d;
}
__device__ inline float2 pk_add(float2 a, float2 b) {
  float2 d;
  asm("v_pk_add_f32 %0, %1, %2" : "=v"(d) : "v"(a), "v"(b));
  return d;
}

// f32 DPP max step: shifted-in lanes get 0.0 (identity for dd >= 0)
#define DPPMAXF(ctrl)                                                          \
  {                                                                            \
    unsigned _o = (unsigned)__builtin_amdgcn_update_dpp(                       \
        0, (int)__float_as_uint(m), (ctrl), 0xF, 0xF, true);                   \
    m = fmaxf(m, __uint_as_float(_o));                                         \
  }

__global__ __launch_bounds__(512) void fps_kernel(const float* __restrict__ xyzs,
                                                  float* __restrict__ out) {
#pragma clang fp contract(off)
  const int bt  = blockIdx.x & 15;       // 16 redundant copies per frame
  const int tid = threadIdx.x;           // 0..511
  __shared__ float sx[N_PTS], syy[N_PTS], szz[N_PTS];
  __shared__ __align__(16) unsigned swp[2][16];   // 8 waves x (valbits, gi), dbuf
  __shared__ int sidx[M_PTS];

  const float* f = xyzs + (size_t)bt * (N_PTS * 3);
  for (int i = tid; i < N_PTS; i += 512) {
    sx[i]  = f[3 * i + 0];
    syy[i] = f[3 * i + 1];
    szz[i] = f[3 * i + 2];
  }
  if (tid == 0) sidx[0] = 0;
  __syncthreads();

  // consecutive layout: thread owns points [8*tid, 8*tid+8)
  const int base = tid << 3;
  float2 px2[4], py2[4], pz2[4], dd2[4];
#pragma unroll
  for (int j = 0; j < 4; ++j) {
    int i0 = base + 2 * j;
    px2[j] = {sx[i0], sx[i0 + 1]};
    py2[j] = {syy[i0], syy[i0 + 1]};
    pz2[j] = {szz[i0], szz[i0 + 1]};
    dd2[j] = {1e10f, 1e10f};
  }
  float wx = sx[0], wy = syy[0], wz = szz[0];

  for (int it = 1; it < M_PTS; ++it) {
    float2 wxx = {wx, wx}, wyy = {wy, wy}, wzz = {wz, wz};
    // packed distance update: d = (dx*dx + dy*dy) + dz*dz (exact numpy order)
#pragma unroll
    for (int j = 0; j < 4; ++j) {
      float2 dx = pk_sub(px2[j], wxx);
      float2 dy = pk_sub(py2[j], wyy);
      float2 dz = pk_sub(pz2[j], wzz);
      float2 m1 = pk_mul(dx, dx);
      float2 m2 = pk_mul(dy, dy);
      float2 s  = pk_add(m1, m2);
      float2 m3 = pk_mul(dz, dz);
      float2 dt = pk_add(s, m3);
      dd2[j].x = fminf(dd2[j].x, dt.x);
      dd2[j].y = fminf(dd2[j].y, dt.y);
    }
    // strict-> tree over 8 local values (challenger always higher index)
    float v4[4]; int s4[4];
#pragma unroll
    for (int a = 0; a < 4; ++a) {
      bool t = dd2[a].y > dd2[a].x;
      v4[a] = t ? dd2[a].y : dd2[a].x;
      s4[a] = 2 * a + (t ? 1 : 0);
    }
    float v2[2]; int s2v[2];
#pragma unroll
    for (int a = 0; a < 2; ++a) {
      bool t = v4[2 * a + 1] > v4[2 * a];
      v2[a] = t ? v4[2 * a + 1] : v4[2 * a];
      s2v[a] = t ? s4[2 * a + 1] : s4[2 * a];
    }
    bool t1 = v2[1] > v2[0];
    float bv = t1 ? v2[1] : v2[0];
    int   bj = t1 ? s2v[1] : s2v[0];     // local index 0..7

    // wave max on VALUE only (f32 DPP chain, result in lane 63)
    float m = bv;
    DPPMAXF(0x111);  // row_shr:1
    DPPMAXF(0x112);  // row_shr:2
    DPPMAXF(0x114);  // row_shr:4
    DPPMAXF(0x118);  // row_shr:8
    DPPMAXF(0x142);  // row_bcast:15
    DPPMAXF(0x143);  // row_bcast:31
    float vmax = __uint_as_float(
        (unsigned)__builtin_amdgcn_readlane((int)__float_as_uint(m), 63));
    // index recovery: first matching lane = min tid = min gi (consecutive layout)
    bool match = (bv == vmax);
    unsigned long long mk = __ballot(match);
    int wl  = __builtin_ctzll(mk);
    int bjw = __builtin_amdgcn_readlane(bj, wl);
    const int w = tid >> 6;
    unsigned gi = (unsigned)((((w << 6) + wl) << 3) + bjw);

    const int p = it & 1;
    if ((tid & 63) == 63) {
      swp[p][2 * w]     = __float_as_uint(vmax);
      swp[p][2 * w + 1] = gi;
    }
    __syncthreads();
    // cross-wave select on (val,gi): uint compare == f32 compare for vals >= 0;
    // strict > keeps earlier wave (smaller gi) on ties.
    uint4 A = *(const uint4*)&swp[p][0];    // w0(v,g) w1(v,g)
    uint4 Bq = *(const uint4*)&swp[p][4];   // w2 w3
    uint4 Cq = *(const uint4*)&swp[p][8];   // w4 w5
    uint4 Dq = *(const uint4*)&swp[p][12];  // w6 w7
    unsigned va, ga, vb, gb, vc, gc, vd, gd;
    { bool t = A.z  > A.x;  va = t ? A.z  : A.x;  ga = t ? A.w  : A.y;  }
    { bool t = Bq.z > Bq.x; vb = t ? Bq.z : Bq.x; gb = t ? Bq.w : Bq.y; }
    { bool t = Cq.z > Cq.x; vc = t ? Cq.z : Cq.x; gc = t ? Cq.w : Cq.y; }
    { bool t = Dq.z > Dq.x; vd = t ? Dq.z : Dq.x; gd = t ? Dq.w : Dq.y; }
    { bool t = vb > va; va = t ? vb : va; ga = t ? gb : ga; }
    { bool t = vd > vc; vc = t ? vd : vc; gc = t ? gd : gc; }
    { bool t = vc > va; va = t ? vc : va; ga = t ? gc : ga; }
    int bi = (int)ga;
    wx = sx[bi]; wy = syy[bi]; wz = szz[bi];
    if (tid == 0) sidx[it] = bi;
  }
  __syncthreads();
  float* orow = out + (size_t)bt * (M_PTS * 3);
  for (int i = tid; i < M_PTS; i += 512) {
    int ix = sidx[i];
    orow[3 * i + 0] = sx[ix];
    orow[3 * i + 1] = syy[ix];
    orow[3 * i + 2] = szz[ix];
  }
}

// ---------------------------------------------------------------- ball query
__global__ __launch_bounds__(256) void ball_kernel(const float* __restrict__ xyzs,
                                                   const float* __restrict__ refpts,
                                                   float* __restrict__ disp4) {
#pragma clang fp contract(off)
  const int lane = threadIdx.x & 63;
  const int gw   = (blockIdx.x << 2) + (threadIdx.x >> 6);   // ref point id, 0..16383
  const int bt   = gw >> 10;
  const float* f = xyzs + (size_t)bt * (N_PTS * 3);
  const float* r = refpts + (size_t)gw * 3;
  const float rx = r[0], ry = r[1], rz = r[2];
  float* dout = disp4 + (size_t)gw * (KNB * 4);

  int filled = 0;
  float p0x = 0.f, p0y = 0.f, p0z = 0.f;
  bool got0 = false;

  for (int base = 0; base < N_PTS; base += 64) {
    if (filled >= KNB) break;
    int j = base + lane;
    float x = f[3 * j], y = f[3 * j + 1], z = f[3 * j + 2];
    float dx = rx - x, dy = ry - y, dz = rz - z;
    float d2 = (dx * dx + dy * dy) + dz * dz;     // exact numpy order
    bool pred = d2 < 0.81f;                       // == f32(0.9*0.9 in f64)
    unsigned long long mk = __ballot(pred);
    if (!got0 && mk) {                            // wave-uniform
      int src = __builtin_ctzll(mk);
      p0x = __shfl(-dx, src); p0y = __shfl(-dy, src); p0z = __shfl(-dz, src);
      got0 = true;
    }
    int slot = filled + __popcll(mk & ((1ull << lane) - 1));
    if (pred && slot < KNB) {
      float4 v; v.x = -dx; v.y = -dy; v.z = -dz; v.w = 0.f;  // xyz - ref
      *(float4*)(dout + slot * 4) = v;
    }
    filled += __popcll(mk);
  }
  if (filled < KNB) {                             // pad with first neighbor
    for (int s = filled + lane; s < KNB; s += 64) {
      float4 v; v.x = p0x; v.y = p0y; v.z = p0z; v.w = 0.f;
      *(float4*)(dout + s * 4) = v;
    }
  }
}

// ---------------------------------------------------------------- BN1 moments
__global__ __launch_bounds__(256) void stats1_kernel(const float* __restrict__ disp4,
                                                     float* __restrict__ acc) {
  const int t = blockIdx.x >> 5, chunk = blockIdx.x & 31;
  const int tid = threadIdx.x;
  float s[9];
#pragma unroll
  for (int q = 0; q < 9; ++q) s[q] = 0.f;
  for (int i = tid; i < 2048; i += 256) {
    int smp = (chunk << 11) + i;                                    // sample in [0,65536)
    size_t flat = ((size_t)(smp >> 15) << 18) + ((size_t)t << 15) + (smp & 32767);
    float4 v = ((const float4*)disp4)[flat];
    s[0] += v.x;       s[1] += v.y;       s[2] += v.z;
    s[3] += v.x * v.x; s[4] += v.y * v.y; s[5] += v.z * v.z;
    s[6] += v.x * v.y; s[7] += v.x * v.z; s[8] += v.y * v.z;
  }
#pragma unroll
  for (int q = 0; q < 9; ++q) {
#pragma unroll
    for (int off = 1; off < 64; off <<= 1) s[q] += __shfl_xor(s[q], off);
  }
  if ((tid & 63) == 0) {
    float* a = acc + t * 9;
#pragma unroll
    for (int q = 0; q < 9; ++q) atomicAdd(&a[q], s[q]);
  }
}

__global__ void fold1_kernel(const float* __restrict__ acc, const float* __restrict__ W1,
                             const float* __restrict__ g1, const float* __restrict__ b1,
                             float* __restrict__ w1p) {
  const int t = blockIdx.x, c = threadIdx.x;
  const float inv_n = 1.0f / 65536.0f;
  const float* a = acc + t * 9;
  float mx = a[0] * inv_n, my = a[1] * inv_n, mz = a[2] * inv_n;
  float Sxx = a[3] * inv_n, Syy = a[4] * inv_n, Szz = a[5] * inv_n;
  float Sxy = a[6] * inv_n, Sxz = a[7] * inv_n, Syz = a[8] * inv_n;
  float w0 = W1[c * 4], w1 = W1[c * 4 + 1], w2 = W1[c * 4 + 2];
  float mean = w0 * mx + w1 * my + w2 * mz;
  float E2 = w0 * w0 * Sxx + w1 * w1 * Syy + w2 * w2 * Szz
           + 2.f * (w0 * w1 * Sxy + w0 * w2 * Sxz + w1 * w2 * Syz);
  float var = E2 - mean * mean;
  float al = g1[c] / sqrtf(var + 1e-5f);
  float4 o; o.x = w0 * al; o.y = w1 * al; o.z = w2 * al; o.w = b1[c] - mean * al;
  ((float4*)w1p)[t * 64 + c] = o;
}

// ---------------------------------------------------------------- Gram of y1
__global__ __launch_bounds__(256) void gram_kernel(const float* __restrict__ disp4,
                                                   const float* __restrict__ w1p,
                                                   float* __restrict__ sumy,
                                                   float* __restrict__ G) {
  const int t = blockIdx.x >> 5, chunk = blockIdx.x & 31;
  const int tid = threadIdx.x;
  __shared__ float4 sdisp[32];
  __shared__ float  yt[32][64];
  __shared__ float  red[256];

  const int c = tid & 63, s0 = tid >> 6;
  float4 wc = ((const float4*)w1p)[t * 64 + c];
  const int r0 = (tid >> 4) << 2, q0 = (tid & 15) << 2;
  float acc[16];
#pragma unroll
  for (int q = 0; q < 16; ++q) acc[q] = 0.f;
  float ysum = 0.f;

  for (int b = 0; b < 64; ++b) {
    int sb = (chunk << 11) + (b << 5);
    if (tid < 32) {
      int smp = sb + tid;
      size_t flat = ((size_t)(smp >> 15) << 18) + ((size_t)t << 15) + (smp & 32767);
      sdisp[tid] = ((const float4*)disp4)[flat];
    }
    __syncthreads();
#pragma unroll
    for (int u = 0; u < 8; ++u) {
      int s = s0 * 8 + u;
      float4 d = sdisp[s];
      float y = wc.x * d.x + wc.y * d.y + wc.z * d.z + wc.w;
      y = y > 0.f ? y : 0.f;
      yt[s][c] = y;
      ysum += y;
    }
    __syncthreads();
#pragma unroll
    for (int s = 0; s < 32; ++s) {
      float4 av = *(const float4*)&yt[s][r0];
      float4 bv = *(const float4*)&yt[s][q0];
      acc[0]  += av.x * bv.x; acc[1]  += av.x * bv.y; acc[2]  += av.x * bv.z; acc[3]  += av.x * bv.w;
      acc[4]  += av.y * bv.x; acc[5]  += av.y * bv.y; acc[6]  += av.y * bv.z; acc[7]  += av.y * bv.w;
      acc[8]  += av.z * bv.x; acc[9]  += av.z * bv.y; acc[10] += av.z * bv.z; acc[11] += av.z * bv.w;
      acc[12] += av.w * bv.x; acc[13] += av.w * bv.y; acc[14] += av.w * bv.z; acc[15] += av.w * bv.w;
    }
    __syncthreads();
  }
  red[tid] = ysum;
  __syncthreads();
  if (tid < 64) {
    float v = red[tid] + red[tid + 64] + red[tid + 128] + red[tid + 192];
    atomicAdd(&sumy[t * 64 + tid], v);
  }
  float* Gp = G + t * 4096;
#pragma unroll
  for (int i = 0; i < 4; ++i)
#pragma unroll
    for (int j2 = 0; j2 < 4; ++j2)
      atomicAdd(&Gp[(r0 + i) * 64 + q0 + j2], acc[i * 4 + j2]);
}

// ---------------------------------------------------------------- BN2 fold
__global__ __launch_bounds__(256) void fold2a_kernel(const float* __restrict__ G,
                                                     const float* __restrict__ W2,
                                                     float* __restrict__ P) {
  const int t = blockIdx.x >> 5, grp = blockIdx.x & 31;
  const int idx = (grp << 8) + threadIdx.x;   // 0..8191
  const int i = idx >> 7, c2 = idx & 127;
  const float* g = G + t * 4096 + i * 64;
  const float* w = W2 + c2 * 64;
  float accv = 0.f;
#pragma unroll
  for (int j = 0; j < 64; ++j) accv += g[j] * w[j];
  P[t * 8192 + i * 128 + c2] = accv;
}

__global__ __launch_bounds__(256) void fold2b_kernel(const float* __restrict__ P,
    const float* __restrict__ sumy, const float* __restrict__ W2,
    const float* __restrict__ g2, const float* __restrict__ b2,
    float* __restrict__ w2p, float* __restrict__ beta2) {
  const int gidx = blockIdx.x * 256 + threadIdx.x;  // 0..1023
  const int t = gidx >> 7, c2 = gidx & 127;
  const float inv_n = 1.f / 65536.f;
  const float* w = W2 + c2 * 64;
  float mean2 = 0.f, E2 = 0.f;
#pragma unroll
  for (int j = 0; j < 64; ++j) mean2 += w[j] * (sumy[t * 64 + j] * inv_n);
  const float* p = P + t * 8192 + c2;
#pragma unroll
  for (int i2 = 0; i2 < 64; ++i2) E2 += w[i2] * p[i2 * 128];
  E2 *= inv_n;
  float var = E2 - mean2 * mean2;
  float al = g2[c2] / sqrtf(var + 1e-5f);
  float be = b2[c2] - mean2 * al;
  beta2[t * 128 + c2] = be;
  float* wo = w2p + (size_t)(t * 128 + c2) * 64;
#pragma unroll
  for (int j = 0; j < 64; ++j) wo[j] = al * w[j];
}

// ---------------------------------------------------------------- final fused GEMM + max_k
// 4 m's per block: w2r register load amortized 4x, 4x fewer blocks.
__global__ __launch_bounds__(256) void final_kernel(
    const float* __restrict__ disp4, const float* __restrict__ w1p,
    const float* __restrict__ w2p, const float* __restrict__ beta2,
    float* __restrict__ outfeat) {
  const int bid = blockIdx.x;        // 4096 = one (bt, m-quad)
  const int bt = bid >> 8, mbase = (bid & 255) << 2;
  const int t = bt & 7;
  const int tid = threadIdx.x;
  __shared__ float4 sdisp[128];      // 4 m x 32 nb
  __shared__ float  sy[128][64];     // 32 KB
  __shared__ float  red[4][128];

  if (tid < 128)
    sdisp[tid] = ((const float4*)disp4)[(size_t)(bt * 1024 + mbase) * 32 + tid];
  const int c = tid & 63;
  float4 w1c = ((const float4*)w1p)[t * 64 + c];
  __syncthreads();

  const int s0 = tid >> 6;           // 0..3
#pragma unroll
  for (int u = 0; u < 32; ++u) {     // each thread: 32 y's (4m x 8s per c)
    int s = s0 * 32 + u;             // 0..127
    float4 d = sdisp[s];
    float y = w1c.x * d.x + w1c.y * d.y + w1c.z * d.z + w1c.w;
    sy[s][c] = y > 0.f ? y : 0.f;
  }

  const int c2 = tid & 127, kh = tid >> 7;
  const float* wr = w2p + (size_t)(t * 128 + c2) * 64;
  float w2r[64];
#pragma unroll
  for (int q = 0; q < 16; ++q) {
    float4 v = ((const float4*)wr)[q];
    w2r[4 * q] = v.x; w2r[4 * q + 1] = v.y; w2r[4 * q + 2] = v.z; w2r[4 * q + 3] = v.w;
  }
  const float b2v = beta2[t * 128 + c2];
  __syncthreads();

#pragma unroll
  for (int mi = 0; mi < 4; ++mi) {
    float mx = 0.0f;                                // relu output >= 0
#pragma unroll
    for (int ki = 0; ki < 16; ++ki) {
      int k = mi * 32 + kh * 16 + ki;
      float a0 = b2v;
#pragma unroll
      for (int j = 0; j < 64; j += 4) {
        float4 yv = *(const float4*)&sy[k][j];
        a0 += yv.x * w2r[j] + yv.y * w2r[j + 1] + yv.z * w2r[j + 2] + yv.w * w2r[j + 3];
      }
      mx = fmaxf(mx, a0);
    }
    if (kh == 1) red[mi][c2] = mx;
    __syncthreads();
    if (kh == 0) {
      mx = fmaxf(mx, red[mi][c2]);
      outfeat[((size_t)(bt * 128 + c2)) * 1024 + mbase + mi] = mx;
    }
  }
}

// ---------------------------------------------------------------- launch
extern "C" void kernel_launch(void* const* d_in, const int* in_sizes, int n_in,
                              void* d_out, int out_size, void* d_ws, size_t ws_size,
                              hipStream_t stream) {
  const float* xyzs = (const float*)d_in[0];
  const float* W1   = (const float*)d_in[1];
  const float* g1   = (const float*)d_in[2];
  const float* b1   = (const float*)d_in[3];
  const float* W2   = (const float*)d_in[4];
  const float* g2   = (const float*)d_in[5];
  const float* b2   = (const float*)d_in[6];
  float* out = (float*)d_out;
  float* ws  = (float*)d_ws;

  float* disp4 = ws;                 // 2,097,152 floats (B,T,M,K,4)
  float* acc   = ws + 2097152;       // 72
  float* sumy  = ws + 2097224;       // 512
  float* G     = ws + 2097736;       // 32768
  float* w1p   = ws + 2130504;       // 2048
  float* P     = ws + 2132552;       // 65536
  float* w2p   = ws + 2198088;       // 65536
  float* beta2 = ws + 2263624;       // 1024   (total ~8.6 MB)

  hipMemsetAsync(acc, 0, (72 + 512 + 32768) * sizeof(float), stream);
  fps_kernel   <<<256,   512, 0, stream>>>(xyzs, out);   // 16 copies/frame, 1 block/CU
  ball_kernel  <<<4096,  256, 0, stream>>>(xyzs, out, disp4);
  stats1_kernel<<<256,   256, 0, stream>>>(disp4, acc);
  fold1_kernel <<<8,     64,  0, stream>>>(acc, W1, g1, b1, w1p);
  gram_kernel  <<<256,   256, 0, stream>>>(disp4, w1p, sumy, G);
  fold2a_kernel<<<256,   256, 0, stream>>>(G, W2, P);
  fold2b_kernel<<<4,     256, 0, stream>>>(P, sumy, W2, g2, b2, w2p, beta2);
  final_kernel <<<4096,  256, 0, stream>>>(disp4, w1p, w2p, beta2, out + 49152);
}